// Round 9
// baseline (519.142 us; speedup 1.0000x reference)
//
#include <hip/hip_runtime.h>
#include <cmath>

#define NN 8192
#define KK 64
#define DD 256
#define HH 128
#define SET0V 32
#define EE (NN*KK)

typedef float f4_t __attribute__((ext_vector_type(4)));

static constexpr size_t OFF_ADJ  = 0;
static constexpr size_t OFF_FEAT = (size_t)NN * NN;             // 67108864
static constexpr size_t OFF_PROB = OFF_FEAT + (size_t)NN * DD;  // 69206016
static constexpr size_t OFF_PAIR = OFF_PROB + (size_t)EE * 2;   // 70254592
static constexpr size_t OFF_BEF  = OFF_PAIR + (size_t)EE * 2;   // 71303168
static constexpr size_t OFF_AFT  = OFF_BEF + 1;                 // 71303169
static constexpr size_t OFF_LEFT = OFF_AFT + 1;                 // 71303170

// margin for certified fp32 ranking: worst-case fp32-vs-fp64 rank-key error
// is ~1.5e-5 (tree-summed 128-dim dot, g32 quantization ~2.4e-7/elem,
// b1=b2=0, prelu_a=0.25 exact); a pair can only be mis-ordered if its fp32
// gap < 2*eps. 1e-4 gives ~7x cushion. Rows below margin re-rank in fp64.
#define MARGIN 1e-4f

// ---------------------------------------------------------------------------
// k_g: g = feat @ W1 in fp64; emits g64 (for fallback + exactness) AND g32
// (fp32 copy for the fast path), plus feat copy-out and the two scalars.
// ---------------------------------------------------------------------------
__global__ __launch_bounds__(128) void k_g(const float* __restrict__ feat,
                                           const float* __restrict__ W1,
                                           double* __restrict__ g,
                                           float* __restrict__ g32,
                                           f4_t* __restrict__ out_feat,
                                           float* __restrict__ out_scal) {
  __shared__ float sf[8 * DD];  // 8 KiB
  int j = threadIdx.x;          // 0..127 = output col
  int n0 = blockIdx.x * 8;
  const f4_t* fsrc = (const f4_t*)(feat + (size_t)n0 * DD);
  f4_t* fdst = (f4_t*)sf;
  f4_t* odst = out_feat + (size_t)n0 * DD / 4;
#pragma unroll
  for (int t = 0; t < 4; t++) {
    f4_t v = fsrc[j + t * 128];
    fdst[j + t * 128] = v;
    __builtin_nontemporal_store(v, odst + j + t * 128);  // fused feat copy-out
  }
  if (blockIdx.x == 0 && j == 0) {
    out_scal[0] = 64.0f;  // before_edge_num
    out_scal[1] = 32.0f;  // after_edge_num (kept vals >= 0.1, never zero)
  }
  __syncthreads();
  double acc[8];
#pragma unroll
  for (int n = 0; n < 8; n++) acc[n] = 0.0;
  for (int k = 0; k < DD; k += 4) {
    double w0 = (double)W1[(k + 0) * HH + j];
    double w1 = (double)W1[(k + 1) * HH + j];
    double w2 = (double)W1[(k + 2) * HH + j];
    double w3 = (double)W1[(k + 3) * HH + j];
#pragma unroll
    for (int n = 0; n < 8; n++) {
      f4_t f = *(const f4_t*)&sf[n * DD + k];
      acc[n] += (double)f.x * w0;
      acc[n] += (double)f.y * w1;
      acc[n] += (double)f.z * w2;
      acc[n] += (double)f.w * w3;
    }
  }
#pragma unroll
  for (int n = 0; n < 8; n++) {
    g[(size_t)(n0 + n) * HH + j]   = acc[n];
    g32[(size_t)(n0 + n) * HH + j] = (float)acc[n];
  }
}

// ---------------------------------------------------------------------------
// k_main: fused per-row pipeline, one wave per dst row (4 waves/block),
// ZERO barriers (rank via 63-step shfl rotate, degree via shfl butterfly).
//   pass 1 (fp32): gather g32 (half traffic), MLP, rank key d=l1-l0,
//     rank + min pairwise gap in one rotate loop.
//   certify: if row min-gap < MARGIN, whole wave re-runs MLP+rank in fp64
//     (wave-uniform branch; ~3-6% of rows expected).
//   epilogue: kept = rank>=32, fp64 shfl-butterfly degree, s_waitcnt(0) to
//     drain the interleaved nt zero-fill, scatter normalized adj + left_row.
// ---------------------------------------------------------------------------
__global__ __launch_bounds__(256) void k_main(
    const double* __restrict__ g, const float* __restrict__ g32,
    const int* __restrict__ nbr,
    const float* __restrict__ b1, const float* __restrict__ b2,
    const float* __restrict__ pa, const float* __restrict__ W2,
    const float* __restrict__ adj, float* __restrict__ out_adj,
    float* __restrict__ out_prob, float* __restrict__ out_pair,
    float* __restrict__ out_left) {
  int wave = threadIdx.x >> 6;
  int lane = threadIdx.x & 63;
  int r = blockIdx.x * 4 + wave;
  int q = lane >> 4;   // edge slot 0..3
  int s = lane & 15;   // dim segment 0..15

  const int* nrow = nbr + r * KK;
  int c_mine = nrow[lane];                                   // early issue
  float v = __builtin_nontemporal_load(&adj[(size_t)r * NN + c_mine]);  // early

  f4_t* row4 = (f4_t*)(out_adj + (size_t)r * NN);
  const f4_t z = {0.f, 0.f, 0.f, 0.f};

  // fp32 constants (b1==0 in this problem but honored anyway)
  float grb[8], aa[8], w0c[8], w1c[8];
  const float* gr32 = g32 + (size_t)r * HH + s * 8;
#pragma unroll
  for (int d = 0; d < 8; d++) {
    int dim = s * 8 + d;
    grb[d] = gr32[d] + b1[dim];
    aa[d]  = pa[dim];
    w0c[d] = W2[2 * dim];
    w1c[d] = W2[2 * dim + 1];
  }

  float st0 = 0.f, st1 = 0.f;
  for (int grp = 0; grp < 16; grp++) {
    // interleaved zero-fill: 2 nt float4 stores per lane per iteration
    __builtin_nontemporal_store(z, row4 + lane + (2 * grp) * 64);
    __builtin_nontemporal_store(z, row4 + lane + (2 * grp + 1) * 64);

    int c = nrow[grp * 4 + q];
    const float* gc = g32 + (size_t)c * HH + s * 8;
    float t0 = 0.f, t1 = 0.f;
#pragma unroll
    for (int d = 0; d < 8; d++) {
      float h = grb[d] - gc[d];
      h = h >= 0.f ? h : aa[d] * h;
      t0 += h * w0c[d];
      t1 += h * w1c[d];
    }
#pragma unroll
    for (int m = 1; m < 16; m <<= 1) {
      t0 += __shfl_xor(t0, m, 16);
      t1 += __shfl_xor(t1, m, 16);
    }
    if (s == grp) { st0 = t0; st1 = t1; }  // lane q*16+grp keeps edge grp*4+q
  }
  int src = ((lane & 3) << 4) | (lane >> 2);
  float T0 = __shfl(st0, src, 64);
  float T1 = __shfl(st1, src, 64);
  float l0 = T0 + b2[0];
  float l1 = T1 + b2[1];
  float dkey = l1 - l0;                // rank key (monotone in p1)

  // prob / pair outputs (coalesced float2)
  size_t e = (size_t)r * KK + lane;
  float dm = l0 > l1 ? l0 : l1;
  float e0 = expf(l0 - dm), e1 = expf(l1 - dm);
  float inv = 1.0f / (e0 + e1);
  *(float2*)(out_prob + 2 * e) = make_float2(e0 * inv, e1 * inv);
  *(float2*)(out_pair + 2 * e) = make_float2((float)r, (float)c_mine);

  // stable ascending rank + min pairwise gap, barrier-free (shfl rotate)
  int rank = 0;
  float mg = 1e30f;
#pragma unroll 7
  for (int off = 1; off < 64; off++) {
    int j = (lane + off) & 63;
    float qq = __shfl(dkey, j, 64);
    rank += (int)((qq < dkey) || (qq == dkey && j < lane));
    mg = fminf(mg, fabsf(qq - dkey));
  }
#pragma unroll
  for (int m = 1; m < 64; m <<= 1) mg = fminf(mg, __shfl_xor(mg, m, 64));

  if (mg < MARGIN) {
    // certified-unsafe row: re-run MLP + rank fully in fp64 (wave-uniform)
    double grb6[8], aa6[8], w06[8], w16[8];
    const double* gr6 = g + (size_t)r * HH + s * 8;
#pragma unroll
    for (int d = 0; d < 8; d++) {
      int dim = s * 8 + d;
      grb6[d] = gr6[d] + (double)b1[dim];
      aa6[d]  = (double)pa[dim];
      w06[d]  = (double)W2[2 * dim];
      w16[d]  = (double)W2[2 * dim + 1];
    }
    double s0 = 0.0, s1 = 0.0;
    for (int grp = 0; grp < 16; grp++) {
      int c = nrow[grp * 4 + q];
      const double* gc = g + (size_t)c * HH + s * 8;
      double t0 = 0.0, t1 = 0.0;
#pragma unroll
      for (int d = 0; d < 8; d++) {
        double h = grb6[d] - gc[d];
        h = h >= 0.0 ? h : aa6[d] * h;
        t0 += h * w06[d];
        t1 += h * w16[d];
      }
#pragma unroll
      for (int m = 1; m < 16; m <<= 1) {
        t0 += __shfl_xor(t0, m, 16);
        t1 += __shfl_xor(t1, m, 16);
      }
      if (s == grp) { s0 = t0; s1 = t1; }
    }
    double D0 = __shfl(s0, src, 64);
    double D1 = __shfl(s1, src, 64);
    double dk64 = (D1 + (double)b2[1]) - (D0 + (double)b2[0]);
    rank = 0;
    for (int off = 1; off < 64; off++) {
      int j = (lane + off) & 63;
      double qq = __shfl(dk64, j, 64);
      rank += (int)((qq < dk64) || (qq == dk64 && j < lane));
    }
  }

  bool kept = rank >= SET0V;
  // degree via 64-lane shuffle butterfly (fp64, order-independent)
  double dv = kept ? (double)v : 0.0;
#pragma unroll
  for (int m = 1; m < 64; m <<= 1) dv += __shfl_xor(dv, m, 64);

  // drain the nt zero stores before re-dirtying the row through L2
  __builtin_amdgcn_s_waitcnt(0);
  if (kept) {
    out_adj[(size_t)r * NN + c_mine] = (float)((double)v / (dv + 1e-6));
    out_left[(size_t)r * SET0V + (rank - SET0V)] = (float)(r * KK + lane);
  }
}

extern "C" void kernel_launch(void* const* d_in, const int* in_sizes, int n_in,
                              void* d_out, int out_size, void* d_ws, size_t ws_size,
                              hipStream_t stream) {
  const float* adj  = (const float*)d_in[0];
  const float* feat = (const float*)d_in[1];
  const int*   nbr  = (const int*)d_in[2];
  const float* W1   = (const float*)d_in[4];
  const float* b1   = (const float*)d_in[5];
  const float* pa   = (const float*)d_in[6];
  const float* W2   = (const float*)d_in[7];
  const float* b2   = (const float*)d_in[8];
  float* out = (float*)d_out;

  double* g  = (double*)d_ws;                 // 8192*128 doubles = 8 MiB
  float* g32 = (float*)(g + (size_t)NN * HH); // 8192*128 floats  = 4 MiB

  hipLaunchKernelGGL(k_g, dim3(1024), dim3(128), 0, stream,
                     feat, W1, g, g32, (f4_t*)(out + OFF_FEAT), out + OFF_BEF);
  hipLaunchKernelGGL(k_main, dim3(2048), dim3(256), 0, stream,
                     g, g32, nbr, b1, b2, pa, W2, adj,
                     out + OFF_ADJ, out + OFF_PROB, out + OFF_PAIR,
                     out + OFF_LEFT);
}

// Round 10
// 494.173 us; speedup vs baseline: 1.0505x; 1.0505x over previous
//
#include <hip/hip_runtime.h>
#include <cmath>

#define NN 8192
#define KK 64
#define DD 256
#define HH 128
#define SET0V 32
#define EE (NN*KK)

typedef float f4_t __attribute__((ext_vector_type(4)));

static constexpr size_t OFF_ADJ  = 0;
static constexpr size_t OFF_FEAT = (size_t)NN * NN;             // 67108864
static constexpr size_t OFF_PROB = OFF_FEAT + (size_t)NN * DD;  // 69206016
static constexpr size_t OFF_PAIR = OFF_PROB + (size_t)EE * 2;   // 70254592
static constexpr size_t OFF_BEF  = OFF_PAIR + (size_t)EE * 2;   // 71303168
static constexpr size_t OFF_AFT  = OFF_BEF + 1;                 // 71303169
static constexpr size_t OFF_LEFT = OFF_AFT + 1;                 // 71303170

// ---------------------------------------------------------------------------
// k_g: g = feat @ W1 in fp64 ([8192,256]x[256,128] -> [8192,128] doubles),
// plus feat copy-out (non-temporal) and the two scalar outputs.
// 1024 blocks x 128 threads, 8 rows per block.
// ---------------------------------------------------------------------------
__global__ __launch_bounds__(128) void k_g(const float* __restrict__ feat,
                                           const float* __restrict__ W1,
                                           double* __restrict__ g,
                                           f4_t* __restrict__ out_feat,
                                           float* __restrict__ out_scal) {
  __shared__ float sf[8 * DD];  // 8 KiB
  int j = threadIdx.x;          // 0..127 = output col
  int n0 = blockIdx.x * 8;
  const f4_t* fsrc = (const f4_t*)(feat + (size_t)n0 * DD);
  f4_t* fdst = (f4_t*)sf;
  f4_t* odst = out_feat + (size_t)n0 * DD / 4;
#pragma unroll
  for (int t = 0; t < 4; t++) {
    f4_t v = fsrc[j + t * 128];
    fdst[j + t * 128] = v;
    __builtin_nontemporal_store(v, odst + j + t * 128);  // fused feat copy-out
  }
  if (blockIdx.x == 0 && j == 0) {
    out_scal[0] = 64.0f;  // before_edge_num
    out_scal[1] = 32.0f;  // after_edge_num (kept vals >= 0.1, never zero)
  }
  __syncthreads();
  double acc[8];
#pragma unroll
  for (int n = 0; n < 8; n++) acc[n] = 0.0;
  for (int k = 0; k < DD; k += 4) {
    double w0 = (double)W1[(k + 0) * HH + j];
    double w1 = (double)W1[(k + 1) * HH + j];
    double w2 = (double)W1[(k + 2) * HH + j];
    double w3 = (double)W1[(k + 3) * HH + j];
#pragma unroll
    for (int n = 0; n < 8; n++) {
      f4_t f = *(const f4_t*)&sf[n * DD + k];
      acc[n] += (double)f.x * w0;
      acc[n] += (double)f.y * w1;
      acc[n] += (double)f.z * w2;
      acc[n] += (double)f.w * w3;
    }
  }
#pragma unroll
  for (int n = 0; n < 8; n++) g[(size_t)(n0 + n) * HH + j] = acc[n];
}

// ---------------------------------------------------------------------------
// k_main: fully fused per-row pipeline. One wave per dst row (4 rows/block):
//   - early issue: nbr row + adj[r][c] gather (latency hides under MLP)
//   - interleaved nt zero-fill of the 32 KB new_adj row
//   - per-edge MLP in fp64 (16 lanes/edge, coalesced g gathers, butterfly)
//   - rank key d = l1-l0 (fp64, monotone in p1, identical order & ties)
//   - stable rank via LDS, keep rank>=32, fp64 degree, scatter normalized
//     values into the row this same wave just zeroed, emit left_row.
// WAW safety: __syncthreads() lowers to s_waitcnt vmcnt(0)+s_barrier on
// gfx950, so the nt zero stores are drained before the scatter stores.
// NOTE: best-measured configuration (494.2/494.9 us, R5/R7). Rejected by
// measurement: x2 unroll (R6 +25us), 1-wave blocks (R8 +3us),
// fp32-certified rank + shfl-rotate (R9 +25us). Do not re-try without new
// counter evidence.
// ---------------------------------------------------------------------------
__global__ __launch_bounds__(256) void k_main(
    const double* __restrict__ g, const int* __restrict__ nbr,
    const float* __restrict__ b1, const float* __restrict__ b2,
    const float* __restrict__ pa, const float* __restrict__ W2,
    const float* __restrict__ adj, float* __restrict__ out_adj,
    float* __restrict__ out_prob, float* __restrict__ out_pair,
    float* __restrict__ out_left) {
  int wave = threadIdx.x >> 6;
  int lane = threadIdx.x & 63;
  int r = blockIdx.x * 4 + wave;
  int q = lane >> 4;   // edge slot 0..3
  int s = lane & 15;   // dim segment 0..15

  const int* nrow = nbr + r * KK;
  int c_mine = nrow[lane];                                   // early issue
  float v = __builtin_nontemporal_load(&adj[(size_t)r * NN + c_mine]);  // early

  f4_t* row4 = (f4_t*)(out_adj + (size_t)r * NN);
  const f4_t z = {0.f, 0.f, 0.f, 0.f};

  double grb[8], aa[8], w0c[8], w1c[8];
  const double* gr = g + (size_t)r * HH + s * 8;
#pragma unroll
  for (int d = 0; d < 8; d++) {
    int dim = s * 8 + d;
    grb[d] = gr[d] + (double)b1[dim];
    aa[d]  = (double)pa[dim];
    w0c[d] = (double)W2[2 * dim];
    w1c[d] = (double)W2[2 * dim + 1];
  }

  double st0 = 0.0, st1 = 0.0;
  for (int grp = 0; grp < 16; grp++) {
    // interleaved zero-fill: 2 nt float4 stores per lane per iteration
    __builtin_nontemporal_store(z, row4 + lane + (2 * grp) * 64);
    __builtin_nontemporal_store(z, row4 + lane + (2 * grp + 1) * 64);

    int c = nrow[grp * 4 + q];
    const double* gc = g + (size_t)c * HH + s * 8;
    double t0 = 0.0, t1 = 0.0;
#pragma unroll
    for (int d = 0; d < 8; d++) {
      double h = grb[d] - gc[d];
      h = h >= 0.0 ? h : aa[d] * h;
      t0 += h * w0c[d];
      t1 += h * w1c[d];
    }
#pragma unroll
    for (int m = 1; m < 16; m <<= 1) {
      t0 += __shfl_xor(t0, m, 16);
      t1 += __shfl_xor(t1, m, 16);
    }
    if (s == grp) { st0 = t0; st1 = t1; }  // lane q*16+grp keeps edge grp*4+q
  }
  int src = ((lane & 3) << 4) | (lane >> 2);
  double T0 = __shfl(st0, src, 64);
  double T1 = __shfl(st1, src, 64);
  double l0 = T0 + (double)b2[0];
  double l1 = T1 + (double)b2[1];
  double dkey = l1 - l0;               // rank key (monotone in p1)

  // prob / pair outputs (coalesced float2)
  size_t e = (size_t)r * KK + lane;
  float dm = (float)(l0 > l1 ? l0 : l1);
  float e0 = expf((float)l0 - dm), e1 = expf((float)l1 - dm);
  float inv = 1.0f / (e0 + e1);
  *(float2*)(out_prob + 2 * e) = make_float2(e0 * inv, e1 * inv);
  *(float2*)(out_pair + 2 * e) = make_float2((float)r, (float)c_mine);

  // stable ascending rank (ties by index = jnp stable argsort)
  __shared__ double sp[4][64];
  __shared__ double sv[4][64];
  sp[wave][lane] = dkey;
  __syncthreads();  // also drains nt zero stores (vmcnt(0) before s_barrier)
  int rank = 0;
#pragma unroll 8
  for (int j = 0; j < KK; j++) {
    double qq = sp[wave][j];
    rank += (int)((qq < dkey) || (qq == dkey && j < lane));
  }
  bool kept = rank >= SET0V;
  sv[wave][lane] = kept ? (double)v : 0.0;
  __syncthreads();
  double deg = 0.0;
#pragma unroll 8
  for (int j = 0; j < KK; j++) deg += sv[wave][j];
  if (kept) {
    out_adj[(size_t)r * NN + c_mine] = (float)((double)v / (deg + 1e-6));
    out_left[(size_t)r * SET0V + (rank - SET0V)] = (float)(r * KK + lane);
  }
}

extern "C" void kernel_launch(void* const* d_in, const int* in_sizes, int n_in,
                              void* d_out, int out_size, void* d_ws, size_t ws_size,
                              hipStream_t stream) {
  const float* adj  = (const float*)d_in[0];
  const float* feat = (const float*)d_in[1];
  const int*   nbr  = (const int*)d_in[2];
  const float* W1   = (const float*)d_in[4];
  const float* b1   = (const float*)d_in[5];
  const float* pa   = (const float*)d_in[6];
  const float* W2   = (const float*)d_in[7];
  const float* b2   = (const float*)d_in[8];
  float* out = (float*)d_out;

  double* g = (double*)d_ws;  // 8192*128 doubles = 8 MiB

  hipLaunchKernelGGL(k_g, dim3(1024), dim3(128), 0, stream,
                     feat, W1, g, (f4_t*)(out + OFF_FEAT), out + OFF_BEF);
  hipLaunchKernelGGL(k_main, dim3(2048), dim3(256), 0, stream,
                     g, nbr, b1, b2, pa, W2, adj,
                     out + OFF_ADJ, out + OFF_PROB, out + OFF_PAIR,
                     out + OFF_LEFT);
}